// Round 4
// baseline (39104.480 us; speedup 1.0000x reference)
//
#include <hip/hip_runtime.h>
#include <math.h>

#pragma clang fp contract(off)

#define DD 384
#define NS 96
#define PB 32     // panel width (pivots per panel)
#define PW 388    // sp row stride (floats)
#define NW 16     // waves per block

// A = I - P P^T, full symmetric matrix (P = eigfunc[:, :NS])
__global__ void build_A_kernel(const float* __restrict__ eig, float* __restrict__ A) {
    int idx = blockIdx.x * blockDim.x + threadIdx.x;
    if (idx >= DD * DD) return;
    int j = idx / DD, z = idx - j * DD;
    const float* rj = eig + (size_t)j * DD;
    const float* rz = eig + (size_t)z * DD;
    float s = 0.0f;
    for (int c = 0; c < NS; ++c) s = fmaf(rj[c], rz[c], s);
    A[(size_t)j * DD + z] = ((j == z) ? 1.0f : 0.0f) - s;
}

__global__ __launch_bounds__(1024) void sampler_kernel(const float* __restrict__ u,
                                                       float* __restrict__ A,
                                                       float* __restrict__ W,
                                                       float* __restrict__ out) {
    __shared__ float sblk[PB * 33];   // diag block (upper used)
    __shared__ float sp[PB * PW];     // panel rows, col index j = global_col - x0 (j >= bs)
    __shared__ float sinv[PB];
    __shared__ float pivL[DD];
    __shared__ float probs[DD];
    __shared__ int s_pos;

    const int t = threadIdx.x;
    const int wid = t >> 6;
    const int lane = t & 63;
    const int lr = lane >> 4;   // 0..3
    const int lc = lane & 15;   // 0..15

    // Blocked right-looking elimination, bit-exact vs per-pivot rank-1 reference:
    // every element receives c_b = inv_b*(v_b(b,row)*v_b(b,col)) subs in ascending
    // pivot order with identical parenthesization.
    auto do_panels = [&](const float* SRC0, float* DST, int px0, int pend, int cmax,
                         int posAdj, bool spec) {
        for (int x0 = px0; x0 < pend; x0 += PB) {
            const int rem = pend - x0;
            const int bs = (rem < PB) ? rem : PB;
            const int width = cmax - x0;
            const float* SRC = (x0 == px0) ? SRC0 : DST;
            const bool doTrail = !(spec && (x0 + PB >= pend));   // last spec panel: pivots only

            if (wid == 0) {
                // ---- load bs x bs diag block, then factor it (single wave, no barrier) ----
                {
                    const int r0 = lane >> 5;      // 0..1
                    const int c = lane & 31;
                    if (c < bs)
                        for (int r = r0; r < bs; r += 2)
                            sblk[r * 33 + c] = SRC[(size_t)(x0 + r) * DD + (x0 + c)];
                }
                for (int x = 0; x < bs; ++x) {
                    float p = sblk[x * 33 + x];
                    if (x0 + x == posAdj) p = p - 1.0f;
                    const float inv = (fabsf(p) > 1e-30f) ? (1.0f / p) : 0.0f;
                    if (lane == 0) { sinv[x] = inv; pivL[x0 + x] = p; }
                    for (int rr = x + 1; rr < bs; rr += 2) {
                        const int r = rr + (lane >> 5);
                        const int c = lane & 31;
                        if (r < bs && c >= r && c < bs) {
                            float cc = inv * (sblk[x * 33 + r] * sblk[x * 33 + c]);
                            sblk[r * 33 + c] = sblk[r * 33 + c] - cc;
                        }
                    }
                }
            } else if (doTrail) {
                // ---- waves 1..15: load panel rows off-diag cols [bs, width) ----
                for (int i = wid - 1; i < bs; i += NW - 1) {
                    const float* srow = SRC + (size_t)(x0 + i) * DD + x0;
                    for (int j = bs + lane; j < width; j += 64)
                        sp[i * PW + j] = srow[j];
                }
            }
            __syncthreads();

            if (doTrail) {
                // ---- panel-row solve: one column per thread, registers, unrolled ----
                for (int j = bs + t; j < width; j += 1024) {
                    float w[PB];
                    #pragma unroll
                    for (int i = 0; i < PB; ++i)
                        w[i] = (i < bs) ? sp[i * PW + j] : 0.0f;
                    #pragma unroll
                    for (int b = 0; b < PB - 1; ++b) {
                        if (b < bs - 1) {
                            const float invb = sinv[b];
                            const float wb = w[b];
                            #pragma unroll
                            for (int i = b + 1; i < PB; ++i) {
                                if (i < bs) {
                                    float cc = invb * (sblk[b * 33 + i] * wb);
                                    w[i] = w[i] - cc;
                                }
                            }
                        }
                    }
                    #pragma unroll
                    for (int i = 0; i < PB; ++i)
                        if (i < bs) sp[i * PW + j] = w[i];
                }
                __syncthreads();

                // ---- trailing rank-bs update: rows [x0+bs, cmax), cols >= row ----
                const int tb = x0 + bs;
                if (tb < cmax) {
                    int tile = 0;
                    for (int ty = tb; ty < cmax; ty += 16) {
                        for (int tz = ty; tz < cmax; tz += 64) {
                            if ((tile++ & (NW - 1)) != wid) continue;
                            const int ybase = ty + 4 * lr;
                            const int zbase = tz + lc;
                            float wv[4][4];
                            const bool fast = (tz != ty) && (ty + 16 <= cmax) && (tz + 64 <= cmax);
                            if (fast) {
                                #pragma unroll
                                for (int yi = 0; yi < 4; ++yi) {
                                    const float* srow = SRC + (size_t)(ybase + yi) * DD;
                                    #pragma unroll
                                    for (int zi = 0; zi < 4; ++zi)
                                        wv[yi][zi] = srow[zbase + 16 * zi];
                                }
                                for (int b = 0; b < bs; ++b) {
                                    const float inv = sinv[b];
                                    float cy[4], cz[4];
                                    #pragma unroll
                                    for (int yi = 0; yi < 4; ++yi) cy[yi] = sp[b * PW + (ybase + yi - x0)];
                                    #pragma unroll
                                    for (int zi = 0; zi < 4; ++zi) cz[zi] = sp[b * PW + (zbase + 16 * zi - x0)];
                                    #pragma unroll
                                    for (int yi = 0; yi < 4; ++yi) {
                                        #pragma unroll
                                        for (int zi = 0; zi < 4; ++zi) {
                                            float c = inv * (cy[yi] * cz[zi]);
                                            wv[yi][zi] = wv[yi][zi] - c;
                                        }
                                    }
                                }
                                #pragma unroll
                                for (int yi = 0; yi < 4; ++yi) {
                                    float* drow = DST + (size_t)(ybase + yi) * DD;
                                    #pragma unroll
                                    for (int zi = 0; zi < 4; ++zi)
                                        drow[zbase + 16 * zi] = wv[yi][zi];
                                }
                            } else {
                                #pragma unroll
                                for (int yi = 0; yi < 4; ++yi) {
                                    const int y = ybase + yi;
                                    #pragma unroll
                                    for (int zi = 0; zi < 4; ++zi) {
                                        const int z = zbase + 16 * zi;
                                        float v = 0.0f;
                                        if (y < cmax && z < cmax && z >= y) v = SRC[(size_t)y * DD + z];
                                        wv[yi][zi] = v;
                                    }
                                }
                                for (int b = 0; b < bs; ++b) {
                                    const float inv = sinv[b];
                                    #pragma unroll
                                    for (int yi = 0; yi < 4; ++yi) {
                                        const int y = ybase + yi;
                                        const int yy = (y < cmax) ? (y - x0) : 0;
                                        const float cy = sp[b * PW + yy];
                                        #pragma unroll
                                        for (int zi = 0; zi < 4; ++zi) {
                                            const int z = zbase + 16 * zi;
                                            const int zz = (z < cmax) ? (z - x0) : 0;
                                            const float cz = sp[b * PW + zz];
                                            float c = inv * (cy * cz);
                                            wv[yi][zi] = wv[yi][zi] - c;
                                        }
                                    }
                                }
                                #pragma unroll
                                for (int yi = 0; yi < 4; ++yi) {
                                    const int y = ybase + yi;
                                    #pragma unroll
                                    for (int zi = 0; zi < 4; ++zi) {
                                        const int z = zbase + 16 * zi;
                                        if (y < cmax && z < cmax && z >= y)
                                            DST[(size_t)y * DD + z] = wv[yi][zi];
                                    }
                                }
                            }
                        }
                    }
                }
                __syncthreads();
            }
        }
    };

    int xbase = 0;
    for (int k = 0; k < NS; ++k) {
        const int xmax = DD - NS + k + 1;

        // ---- speculative: pivots [xbase, xmax), cols < xmax, A -> W ----
        do_panels(A, W, xbase, xmax, xmax, -1, true);
        __syncthreads();

        // ---- sampling: sequential scalar, bit-faithful to reference ----
        if (t == 0) {
            float cp = 1.0f;
            float tot = 0.0f;
            for (int x = xbase; x < xmax; ++x) {
                const float p = pivL[x];
                float pr = cp * (1.0f - p);
                if (!(fabsf(pr) > 1e-15f)) pr = 0.0f;
                probs[x] = pr;
                tot = tot + pr;
                cp = cp * p;
            }
            const float uk = u[k];
            const float target = uk * tot;
            int cnt = (target > 0.0f) ? xbase : 0;   // zeros below window
            float run = 0.0f;
            for (int x = xbase; x < xmax; ++x) {
                run = run + probs[x];
                if (run < target) ++cnt;
            }
            if (tot < target) cnt += DD - xmax;      // zeros above window
            int pos = (cnt < xmax - 1) ? cnt : (xmax - 1);
            s_pos = pos;
            out[k] = (float)pos;
            out[NS + k] = (pos >= xbase) ? probs[pos] : 0.0f;
        }
        __syncthreads();
        const int pos = s_pos;

        // ---- commit: pivots xbase..pos, full width, in-place on A ----
        do_panels(A, A, xbase, pos + 1, DD, pos, false);

        xbase = pos + 1;
    }
}

extern "C" void kernel_launch(void* const* d_in, const int* in_sizes, int n_in,
                              void* d_out, int out_size, void* d_ws, size_t ws_size,
                              hipStream_t stream) {
    const float* eig = (const float*)d_in[0];
    const float* u   = (const float*)d_in[1];
    float* out = (float*)d_out;
    float* A = (float*)d_ws;
    float* W = A + (size_t)DD * DD;
    build_A_kernel<<<(DD * DD + 255) / 256, 256, 0, stream>>>(eig, A);
    sampler_kernel<<<1, 1024, 0, stream>>>(u, A, W, out);
}